// Round 4
// baseline (627.535 us; speedup 1.0000x reference)
//
#include <hip/hip_runtime.h>
#include <hip/hip_fp16.h>
#include <stdint.h>

typedef _Float16 f16;
typedef __attribute__((ext_vector_type(8))) _Float16 f16x8;
typedef __attribute__((ext_vector_type(4))) float f32x4;

#define D_DIM 4096
#define S_DIM 2048
#define M_DIM 8192   // B*S
#define R_DIM 16
#define KR 128       // K_experts * R
#define KTOT 4224    // D + KR
#define NKT32 132    // KTOT / 32
#define SCALING 2.0f

// ---- ws layout (bytes) ----
#define WS_AP    0                  // A' fp16 [8192][4224]  = 69,206,016
#define WS_WP    69206016           // W' fp16 [4096][4224]  = 34,603,008
#define WS_AH    103809024          // Ah fp16 [128][4096]   =  1,048,576
#define WS_HP    104857600          // h partials fp32 [4][8192][128] = 16,777,216
#define WS_PART  121634816          // colsum partials fp32 [128][4096] = 2,097,152
#define WS_LG    123731968          // logits fp32 [32]
#define WS_WS    123732096          // weights*2.0 fp32 [32]

__device__ __forceinline__ void load_lds16(const void* g, void* l) {
  __builtin_amdgcn_global_load_lds(
      (const __attribute__((address_space(1))) void*)g,
      (__attribute__((address_space(3))) void*)l, 16, 0, 0);
}

union H4 { f16 h[4]; ushort4 u; };

// x [8192][4096] fp32 -> A' cols 0..4095 fp16 ; per-64-row-chunk column sums (no atomics)
__global__ void conv_x(const float* __restrict__ x, f16* __restrict__ Ap,
                       float* __restrict__ part) {
  int rc = blockIdx.x;              // 64-row chunk (128 chunks)
  int cc = blockIdx.y;              // 1024-col chunk (4)
  int col = cc * 1024 + threadIdx.x * 4;
  long base = (long)rc * 64 * D_DIM + col;
  float s0 = 0, s1 = 0, s2 = 0, s3 = 0;
  for (int r = 0; r < 64; ++r) {
    float4 v = *(const float4*)(x + base + (long)r * D_DIM);
    H4 t; t.h[0] = (f16)v.x; t.h[1] = (f16)v.y; t.h[2] = (f16)v.z; t.h[3] = (f16)v.w;
    *(ushort4*)((char*)Ap + ((long)(rc * 64 + r) * KTOT + col) * 2) = t.u;
    s0 += v.x; s1 += v.y; s2 += v.z; s3 += v.w;
  }
  float4 sv; sv.x = s0; sv.y = s1; sv.z = s2; sv.w = s3;
  *(float4*)(part + (long)rc * D_DIM + col) = sv;
}

// base_w [4096][4096] fp32 -> W' cols 0..4095 fp16
__global__ void conv_w(const float* __restrict__ w, f16* __restrict__ Wp) {
  int rc = blockIdx.x;              // 64 chunks
  int cc = blockIdx.y;              // 4
  int col = cc * 1024 + threadIdx.x * 4;
  long base = (long)rc * 64 * D_DIM + col;
  for (int r = 0; r < 64; ++r) {
    float4 v = *(const float4*)(w + base + (long)r * D_DIM);
    H4 t; t.h[0] = (f16)v.x; t.h[1] = (f16)v.y; t.h[2] = (f16)v.z; t.h[3] = (f16)v.w;
    *(ushort4*)((char*)Wp + ((long)(rc * 64 + r) * KTOT + col) * 2) = t.u;
  }
}

// lora_B [8][4096][16] fp32 -> W' cols 4096..4223 : W'[n][4096+k*16+r] = B[k][n][r]
__global__ void conv_bext(const float* __restrict__ loraB, f16* __restrict__ Wp) {
  int g = blockIdx.x * 256 + threadIdx.x;     // 0..524287
  int n = g >> 7, kr = g & 127;
  int k = kr >> 4, r = kr & 15;
  float v = loraB[((long)k * D_DIM + n) * R_DIM + r];
  Wp[(long)n * KTOT + D_DIM + kr] = (f16)v;
}

// lora_A [8][16][4096] fp32 -> Ah [128][4096] fp16 (flat copy+convert)
__global__ void conv_aext(const float* __restrict__ loraA, f16* __restrict__ Ah) {
  long g = ((long)blockIdx.x * 256 + threadIdx.x) * 4;   // over 524288 elems
  float4 v = *(const float4*)(loraA + g);
  H4 t; t.h[0] = (f16)v.x; t.h[1] = (f16)v.y; t.h[2] = (f16)v.z; t.h[3] = (f16)v.w;
  *(ushort4*)((char*)Ah + g * 2) = t.u;
}

// logits[b][k] = dot(colmean[b], router_w[k]) + router_b[k]; colsum from 32 chunk-partials
__global__ void router_logits(const float* __restrict__ part, const float* __restrict__ rw,
                              const float* __restrict__ rb, float* __restrict__ logits) {
  int b = blockIdx.x >> 3, k = blockIdx.x & 7;
  const float* w = rw + k * D_DIM;
  float p = 0.f;
  for (int d = threadIdx.x; d < D_DIM; d += 256) {
    float s = 0.f;
    #pragma unroll 8
    for (int i = 0; i < 32; ++i) s += part[(long)(b * 32 + i) * D_DIM + d];
    p += s * w[d];
  }
  __shared__ float red[4];
  for (int off = 32; off; off >>= 1) p += __shfl_down(p, off);
  if ((threadIdx.x & 63) == 0) red[threadIdx.x >> 6] = p;
  __syncthreads();
  if (threadIdx.x == 0)
    logits[b * 8 + k] = (red[0] + red[1] + red[2] + red[3]) / (float)S_DIM + rb[k];
}

// softmax over K=8 per batch, times SCALING
__global__ void router_softmax(const float* __restrict__ logits, float* __restrict__ wsc) {
  int lane = threadIdx.x;
  if (lane < 32) {
    float L = logits[lane];
    float m = L;
    m = fmaxf(m, __shfl_xor(m, 1));
    m = fmaxf(m, __shfl_xor(m, 2));
    m = fmaxf(m, __shfl_xor(m, 4));
    float e = __expf(L - m);
    float s = e;
    s += __shfl_xor(s, 1); s += __shfl_xor(s, 2); s += __shfl_xor(s, 4);
    wsc[lane] = e / s * SCALING;
  }
}

// sum 4 K-split partials, scale by router weight, write A' ext cols as fp16
__global__ void combine_h(const float* __restrict__ hp, const float* __restrict__ wsc,
                          f16* __restrict__ Ap) {
  long g = (long)blockIdx.x * 256 + threadIdx.x;    // 0..1048575
  long row = g >> 7; int kr = (int)(g & 127);
  int b = (int)(row >> 11);
  float s = hp[g] + hp[g + 1048576] + hp[g + 2097152] + hp[g + 3145728];
  Ap[row * KTOT + D_DIM + kr] = (f16)(s * wsc[b * 8 + (kr >> 4)]);
}

// ---- staging helpers: linear LDS dest + pre-swizzled global source (T2, rule #21) ----
// BK=64 rows (128 B): swizzle byte ^= (row&7)<<4.  256-thread, 128-row tile.
__device__ __forceinline__ void stage128(const f16* __restrict__ G, long row0, int ld,
                                         long kbase, char* ldsT, int tid) {
  int lr = tid >> 3;                                        // 0..31
  int sw = (((tid & 7) * 16) ^ ((lr & 7) << 4)) >> 1;
  char* wbase = ldsT + ((tid >> 6) << 10);
  #pragma unroll
  for (int j = 0; j < 4; ++j) {
    const f16* g = G + (row0 + j * 32 + lr) * (long)ld + kbase + sw;
    load_lds16(g, wbase + j * 4096);
  }
}
// BK=32 rows (64 B): swizzle byte ^= ((row>>1)&3)<<4.  512-thread, 256-row tile, 2 loads.
__device__ __forceinline__ void stage32(const f16* __restrict__ G, long row0, int ld,
                                        long kbase, char* ldsT, int tid) {
  int r = tid >> 2;                                         // 0..127 (row within round)
  int c = (tid & 3) * 16;                                   // byte col in 64-B row
  int swc = (c ^ (((r >> 1) & 3) << 4)) >> 1;               // pre-swizzled col (f16 units)
  char* wbase = ldsT + ((tid >> 6) << 10);                  // wave-uniform LDS base
  #pragma unroll
  for (int j = 0; j < 2; ++j) {
    const f16* g = G + (row0 + j * 128 + r) * (long)ld + kbase + swc;
    load_lds16(g, wbase + j * 8192);
  }
}

// ---------------- h-path GEMM: 128x128 tile, counted-vmcnt pipeline ----------------
// hp[z][M][128] = A[:, z*1024:(z+1)*1024] @ Bt[0:128,:]^T   (z = blockIdx.y)
__global__ __launch_bounds__(256, 2) void gemm_h2(
    const f16* __restrict__ A, int lda, const f16* __restrict__ Bt, int ldb,
    float* __restrict__ hp) {
  __shared__ __align__(16) char smem[65536];   // dbuf x (A 16K + B 16K)
  int tid = threadIdx.x;
  int wave = tid >> 6, lane = tid & 63;
  int wr = wave >> 1, wc = wave & 1;           // 2x2 waves; wave tile 64x64
  int fr = lane & 15, fq = lane >> 4;
  long row0 = (long)blockIdx.x * 128;
  long koff = (long)blockIdx.y * 1024;

  f32x4 acc[4][4] = {};

  stage128(A,  row0, lda, koff,      smem,         tid);
  stage128(Bt, 0,    ldb, koff,      smem + 16384, tid);
  stage128(A,  row0, lda, koff + 64, smem + 32768, tid);
  stage128(Bt, 0,    ldb, koff + 64, smem + 49152, tid);
  asm volatile("s_waitcnt vmcnt(8)" ::: "memory");
  asm volatile("s_barrier" ::: "memory");

  int cur = 0;
  int sw = (fr & 7) << 4;
  for (int t = 0; t < 16; ++t) {
    const char* Ab = smem + cur * 32768;
    const char* Bb = Ab + 16384;
    #pragma unroll
    for (int ks = 0; ks < 2; ++ks) {
      int kb = ks * 64 + fq * 16;
      f16x8 af[4], bf[4];
      #pragma unroll
      for (int mi = 0; mi < 4; ++mi)
        af[mi] = *(const f16x8*)(Ab + (wr * 64 + mi * 16 + fr) * 128 + (kb ^ sw));
      #pragma unroll
      for (int ni = 0; ni < 4; ++ni)
        bf[ni] = *(const f16x8*)(Bb + (wc * 64 + ni * 16 + fr) * 128 + (kb ^ sw));
      #pragma unroll
      for (int mi = 0; mi < 4; ++mi)
        #pragma unroll
        for (int ni = 0; ni < 4; ++ni)
          acc[mi][ni] = __builtin_amdgcn_mfma_f32_16x16x32_f16(af[mi], bf[ni], acc[mi][ni], 0, 0, 0);
    }
    asm volatile("s_barrier" ::: "memory");     // all waves done reading buf[cur]
    if (t + 2 < 16) {
      stage128(A,  row0, lda, koff + (t + 2) * 64, smem + cur * 32768,         tid);
      stage128(Bt, 0,    ldb, koff + (t + 2) * 64, smem + cur * 32768 + 16384, tid);
      asm volatile("s_waitcnt vmcnt(8)" ::: "memory");  // tile t+1 landed
    } else {
      asm volatile("s_waitcnt vmcnt(0)" ::: "memory");
    }
    asm volatile("s_barrier" ::: "memory");
    cur ^= 1;
  }

  long zb = (long)blockIdx.y * (long)M_DIM * 128;
  #pragma unroll
  for (int ni = 0; ni < 4; ++ni) {
    int col = wc * 64 + ni * 16 + fr;
    #pragma unroll
    for (int mi = 0; mi < 4; ++mi) {
      long row = row0 + wr * 64 + mi * 16 + fq * 4;
      float* cp = hp + zb + row * 128 + col;
      #pragma unroll
      for (int j = 0; j < 4; ++j) cp[(long)j * 128] = acc[mi][ni][j];
    }
  }
}

// -------- main 256^2 GEMM: BK=32, 4-buffer depth-3 counted-vmcnt pipeline + T2 + T1 ----
// out[M][ldc] = A[M][lda] @ Bt[N][ldb]^T + bias, K = nkt*32
// LDS: 4 buf x (A 256x32 f16 = 16KB + B 16KB) = 128 KB. 8 waves (2x4), wave tile 128x64.
// Pipeline: 3 tiles in flight (4 loads/thread each); steady-state wait = vmcnt(8)
// (tile t+1 landed, t+2/t+3 flying) -> latency budget ~2 K-steps ~900+ cyc.
__global__ __launch_bounds__(512, 2) void gemm256(
    const f16* __restrict__ A, int lda, const f16* __restrict__ Bt, int ldb,
    int nkt, const float* __restrict__ bias, float* __restrict__ C, int ldc) {
  __shared__ __align__(16) char smem[131072];
  int tid = threadIdx.x;
  int wave = tid >> 6, lane = tid & 63;
  int wr = wave >> 2, wc = wave & 3;        // 2 x 4 wave grid; wave tile 128 x 64
  int fr = lane & 15, fq = lane >> 4;

  // bijective XCD swizzle: 512 wgs = 64 per XCD; n-tile fastest within an XCD
  int flat = blockIdx.x;
  int wg = (flat & 7) * 64 + (flat >> 3);
  long row0 = (long)(wg >> 4) * 256;
  long col0 = (long)(wg & 15) * 256;

  f32x4 acc[8][4] = {};

  // prologue: stage tiles 0,1,2 into buffers 0,1,2 (4 loads/thread each)
  stage32(A,  row0, lda, 0,  smem,                 tid);
  stage32(Bt, col0, ldb, 0,  smem + 16384,         tid);
  stage32(A,  row0, lda, 32, smem + 32768,         tid);
  stage32(Bt, col0, ldb, 32, smem + 32768 + 16384, tid);
  stage32(A,  row0, lda, 64, smem + 65536,         tid);
  stage32(Bt, col0, ldb, 64, smem + 65536 + 16384, tid);
  asm volatile("s_waitcnt vmcnt(8)" ::: "memory");   // tile 0 landed
  asm volatile("s_barrier" ::: "memory");

  // read-side swizzle is lane-constant: byte ^= ((row>>1)&3)<<4 with row%16 = fr
  int sw = (fq * 16) ^ (((fr >> 1) & 3) << 4);
  for (int t = 0; t < nkt; ++t) {
    const char* Ab = smem + (t & 3) * 32768;
    const char* Bb = Ab + 16384;
    f16x8 af[8], bf[4];
    #pragma unroll
    for (int m2 = 0; m2 < 8; ++m2)
      af[m2] = *(const f16x8*)(Ab + (wr * 128 + m2 * 16 + fr) * 64 + sw);
    #pragma unroll
    for (int n2 = 0; n2 < 4; ++n2)
      bf[n2] = *(const f16x8*)(Bb + (wc * 64 + n2 * 16 + fr) * 64 + sw);
    #pragma unroll
    for (int m2 = 0; m2 < 8; ++m2)
      #pragma unroll
      for (int n2 = 0; n2 < 4; ++n2)
        acc[m2][n2] = __builtin_amdgcn_mfma_f32_16x16x32_f16(af[m2], bf[n2], acc[m2][n2], 0, 0, 0);

    if (t + 1 >= nkt) break;                        // last tile: no more staging/waits
    asm volatile("s_barrier" ::: "memory");         // all waves done reading buf[t&3]
    if (t + 3 < nkt) {
      char* dst = smem + ((t + 3) & 3) * 32768;
      stage32(A,  row0, lda, (long)(t + 3) * 32, dst,         tid);
      stage32(Bt, col0, ldb, (long)(t + 3) * 32, dst + 16384, tid);
    }
    // in-flight tiles: t+1 .. min(t+3, nkt-1); need t+1 landed
    int hi = (t + 3 < nkt) ? (t + 3) : (nkt - 1);
    int cnt = (hi - (t + 1)) * 4;
    if (cnt == 8)      asm volatile("s_waitcnt vmcnt(8)" ::: "memory");
    else if (cnt == 4) asm volatile("s_waitcnt vmcnt(4)" ::: "memory");
    else               asm volatile("s_waitcnt vmcnt(0)" ::: "memory");
    asm volatile("s_barrier" ::: "memory");
  }

  #pragma unroll
  for (int ni = 0; ni < 4; ++ni) {
    long col = col0 + wc * 64 + ni * 16 + fr;
    float bv = bias[col];
    #pragma unroll
    for (int mi = 0; mi < 8; ++mi) {
      long row = row0 + wr * 128 + mi * 16 + fq * 4;
      float* cp = C + row * ldc + col;
      #pragma unroll
      for (int j = 0; j < 4; ++j) cp[(long)j * ldc] = acc[mi][ni][j] + bv;
    }
  }
}

extern "C" void kernel_launch(void* const* d_in, const int* in_sizes, int n_in,
                              void* d_out, int out_size, void* d_ws, size_t ws_size,
                              hipStream_t stream) {
  (void)in_sizes; (void)n_in; (void)out_size; (void)ws_size;
  const float* x        = (const float*)d_in[0];
  const float* base_w   = (const float*)d_in[1];
  const float* base_b   = (const float*)d_in[2];
  const float* lora_A   = (const float*)d_in[3];
  const float* lora_B   = (const float*)d_in[4];
  const float* router_w = (const float*)d_in[5];
  const float* router_b = (const float*)d_in[6];
  float* out = (float*)d_out;

  char* ws = (char*)d_ws;
  f16* Ap       = (f16*)(ws + WS_AP);
  f16* Wp       = (f16*)(ws + WS_WP);
  f16* Ah       = (f16*)(ws + WS_AH);
  float* hp     = (float*)(ws + WS_HP);
  float* part   = (float*)(ws + WS_PART);
  float* logits = (float*)(ws + WS_LG);
  float* wsc    = (float*)(ws + WS_WS);

  conv_x<<<dim3(128, 4), 256, 0, stream>>>(x, Ap, part);
  conv_w<<<dim3(64, 4), 256, 0, stream>>>(base_w, Wp);
  conv_bext<<<2048, 256, 0, stream>>>(lora_B, Wp);
  conv_aext<<<512, 256, 0, stream>>>(lora_A, Ah);
  router_logits<<<32, 256, 0, stream>>>(part, router_w, router_b, logits);
  router_softmax<<<1, 64, 0, stream>>>(logits, wsc);
  // h partials: M=8192, N=128, K split 4x1024 — pipelined 128^2 tiles
  gemm_h2<<<dim3(64, 4), 256, 0, stream>>>(Ap, KTOT, Ah, D_DIM, hp);
  combine_h<<<4096, 256, 0, stream>>>(hp, wsc, Ap);
  // main fused GEMM: out = [x|h'] @ [W|Bcat]^T + bias  (K = 4224 = 132*32)
  gemm256<<<512, 512, 0, stream>>>(Ap, KTOT, Wp, KTOT, NKT32, base_b, out, D_DIM);
}

// Round 5
// 582.164 us; speedup vs baseline: 1.0779x; 1.0779x over previous
//
#include <hip/hip_runtime.h>
#include <hip/hip_fp16.h>
#include <stdint.h>

typedef _Float16 f16;
typedef __attribute__((ext_vector_type(8))) _Float16 f16x8;
typedef __attribute__((ext_vector_type(4))) float f32x4;

#define D_DIM 4096
#define S_DIM 2048
#define M_DIM 8192   // B*S
#define R_DIM 16
#define KR 128       // K_experts * R
#define KTOT 4224    // D + KR
#define NKT 66       // KTOT / 64
#define SCALING 2.0f

// ---- ws layout (bytes) ----
#define WS_AP    0                  // A' fp16 [8192][4224]  = 69,206,016
#define WS_WP    69206016           // W' fp16 [4096][4224]  = 34,603,008
#define WS_AH    103809024          // Ah fp16 [128][4096]   =  1,048,576
#define WS_HP    104857600          // h partials fp32 [4][8192][128] = 16,777,216
#define WS_PART  121634816          // colsum partials fp32 [128][4096] = 2,097,152
#define WS_LG    123731968          // logits fp32 [32]
#define WS_WS    123732096          // weights*2.0 fp32 [32]

__device__ __forceinline__ void load_lds16(const void* g, void* l) {
  __builtin_amdgcn_global_load_lds(
      (const __attribute__((address_space(1))) void*)g,
      (__attribute__((address_space(3))) void*)l, 16, 0, 0);
}

union H4 { f16 h[4]; ushort4 u; };

// x [8192][4096] fp32 -> A' cols 0..4095 fp16 ; per-64-row-chunk column sums (no atomics)
__global__ void conv_x(const float* __restrict__ x, f16* __restrict__ Ap,
                       float* __restrict__ part) {
  int rc = blockIdx.x;              // 64-row chunk (128 chunks)
  int cc = blockIdx.y;              // 1024-col chunk (4)
  int col = cc * 1024 + threadIdx.x * 4;
  long base = (long)rc * 64 * D_DIM + col;
  float s0 = 0, s1 = 0, s2 = 0, s3 = 0;
  for (int r = 0; r < 64; ++r) {
    float4 v = *(const float4*)(x + base + (long)r * D_DIM);
    H4 t; t.h[0] = (f16)v.x; t.h[1] = (f16)v.y; t.h[2] = (f16)v.z; t.h[3] = (f16)v.w;
    *(ushort4*)((char*)Ap + ((long)(rc * 64 + r) * KTOT + col) * 2) = t.u;
    s0 += v.x; s1 += v.y; s2 += v.z; s3 += v.w;
  }
  float4 sv; sv.x = s0; sv.y = s1; sv.z = s2; sv.w = s3;
  *(float4*)(part + (long)rc * D_DIM + col) = sv;
}

// base_w [4096][4096] fp32 -> W' cols 0..4095 fp16
__global__ void conv_w(const float* __restrict__ w, f16* __restrict__ Wp) {
  int rc = blockIdx.x;              // 64 chunks
  int cc = blockIdx.y;              // 4
  int col = cc * 1024 + threadIdx.x * 4;
  long base = (long)rc * 64 * D_DIM + col;
  for (int r = 0; r < 64; ++r) {
    float4 v = *(const float4*)(w + base + (long)r * D_DIM);
    H4 t; t.h[0] = (f16)v.x; t.h[1] = (f16)v.y; t.h[2] = (f16)v.z; t.h[3] = (f16)v.w;
    *(ushort4*)((char*)Wp + ((long)(rc * 64 + r) * KTOT + col) * 2) = t.u;
  }
}

// merged small conversions:
//  blocks 0..2047:  lora_B [8][4096][16] -> W'[n][4096+k*16+r]
//  blocks 2048..2559: lora_A [8][16][4096] -> Ah flat fp16
__global__ void conv_small(const float* __restrict__ loraB, const float* __restrict__ loraA,
                           f16* __restrict__ Wp, f16* __restrict__ Ah) {
  if (blockIdx.x < 2048) {
    int g = blockIdx.x * 256 + threadIdx.x;     // 0..524287
    int n = g >> 7, kr = g & 127;
    int k = kr >> 4, r = kr & 15;
    float v = loraB[((long)k * D_DIM + n) * R_DIM + r];
    Wp[(long)n * KTOT + D_DIM + kr] = (f16)v;
  } else {
    long g = ((long)(blockIdx.x - 2048) * 256 + threadIdx.x) * 4;   // over 524288 elems
    float4 v = *(const float4*)(loraA + g);
    H4 t; t.h[0] = (f16)v.x; t.h[1] = (f16)v.y; t.h[2] = (f16)v.z; t.h[3] = (f16)v.w;
    *(ushort4*)((char*)Ah + g * 2) = t.u;
  }
}

// logits[b][k] = dot(colmean[b], router_w[k]) + router_b[k]; colsum from 32 chunk-partials
__global__ void router_logits(const float* __restrict__ part, const float* __restrict__ rw,
                              const float* __restrict__ rb, float* __restrict__ logits) {
  int b = blockIdx.x >> 3, k = blockIdx.x & 7;
  const float* w = rw + k * D_DIM;
  float p = 0.f;
  for (int d = threadIdx.x; d < D_DIM; d += 256) {
    float s = 0.f;
    #pragma unroll 8
    for (int i = 0; i < 32; ++i) s += part[(long)(b * 32 + i) * D_DIM + d];
    p += s * w[d];
  }
  __shared__ float red[4];
  for (int off = 32; off; off >>= 1) p += __shfl_down(p, off);
  if ((threadIdx.x & 63) == 0) red[threadIdx.x >> 6] = p;
  __syncthreads();
  if (threadIdx.x == 0)
    logits[b * 8 + k] = (red[0] + red[1] + red[2] + red[3]) / (float)S_DIM + rb[k];
}

// softmax over K=8 per batch, times SCALING
__global__ void router_softmax(const float* __restrict__ logits, float* __restrict__ wsc) {
  int lane = threadIdx.x;
  if (lane < 32) {
    float L = logits[lane];
    float m = L;
    m = fmaxf(m, __shfl_xor(m, 1));
    m = fmaxf(m, __shfl_xor(m, 2));
    m = fmaxf(m, __shfl_xor(m, 4));
    float e = __expf(L - m);
    float s = e;
    s += __shfl_xor(s, 1); s += __shfl_xor(s, 2); s += __shfl_xor(s, 4);
    wsc[lane] = e / s * SCALING;
  }
}

// sum 4 K-split partials, scale by router weight, write A' ext cols as fp16
__global__ void combine_h(const float* __restrict__ hp, const float* __restrict__ wsc,
                          f16* __restrict__ Ap) {
  long g = (long)blockIdx.x * 256 + threadIdx.x;    // 0..1048575
  long row = g >> 7; int kr = (int)(g & 127);
  int b = (int)(row >> 11);
  float s = hp[g] + hp[g + 1048576] + hp[g + 2097152] + hp[g + 3145728];
  Ap[row * KTOT + D_DIM + kr] = (f16)(s * wsc[b * 8 + (kr >> 4)]);
}

// ---- staging helpers: linear LDS dest + pre-swizzled global source (T2, rule #21) ----
// BK=64 rows (128 B): swizzle byte ^= (row&7)<<4.
// 256-thread version: 32 rows/round, 4 rounds (128-row tile)
__device__ __forceinline__ void stage128(const f16* __restrict__ G, long row0, int ld,
                                         long kbase, char* ldsT, int tid) {
  int lr = tid >> 3;                                        // 0..31
  int sw = (((tid & 7) * 16) ^ ((lr & 7) << 4)) >> 1;
  char* wbase = ldsT + ((tid >> 6) << 10);
  #pragma unroll
  for (int j = 0; j < 4; ++j) {
    const f16* g = G + (row0 + j * 32 + lr) * (long)ld + kbase + sw;
    load_lds16(g, wbase + j * 4096);
  }
}
// 512-thread version: 64 rows/round, 4 rounds (256-row tile)
__device__ __forceinline__ void stage256(const f16* __restrict__ G, long row0, int ld,
                                         long kbase, char* ldsT, int tid) {
  int lr = tid >> 3;                                        // 0..63
  int sw = (((tid & 7) * 16) ^ ((lr & 7) << 4)) >> 1;       // pre-swizzled col (f16 units)
  char* wbase = ldsT + ((tid >> 6) << 10);                  // wave-uniform LDS base
  #pragma unroll
  for (int j = 0; j < 4; ++j) {
    const f16* g = G + (row0 + j * 64 + lr) * (long)ld + kbase + sw;
    load_lds16(g, wbase + j * 8192);
  }
}

// ---------------- h-path GEMM: 128x128 tile, counted-vmcnt pipeline ----------------
// hp[z][M][128] = A[:, z*1024:(z+1)*1024] @ Bt[0:128,:]^T   (z = blockIdx.y)
__global__ __launch_bounds__(256, 2) void gemm_h2(
    const f16* __restrict__ A, int lda, const f16* __restrict__ Bt, int ldb,
    float* __restrict__ hp) {
  __shared__ __align__(16) char smem[65536];   // dbuf x (A 16K + B 16K)
  int tid = threadIdx.x;
  int wave = tid >> 6, lane = tid & 63;
  int wr = wave >> 1, wc = wave & 1;           // 2x2 waves; wave tile 64x64
  int fr = lane & 15, fq = lane >> 4;
  long row0 = (long)blockIdx.x * 128;
  long koff = (long)blockIdx.y * 1024;

  f32x4 acc[4][4] = {};

  stage128(A,  row0, lda, koff,      smem,         tid);
  stage128(Bt, 0,    ldb, koff,      smem + 16384, tid);
  stage128(A,  row0, lda, koff + 64, smem + 32768, tid);
  stage128(Bt, 0,    ldb, koff + 64, smem + 49152, tid);
  asm volatile("s_waitcnt vmcnt(8)" ::: "memory");
  asm volatile("s_barrier" ::: "memory");

  int cur = 0;
  int sw = (fr & 7) << 4;
  for (int t = 0; t < 16; ++t) {
    const char* Ab = smem + cur * 32768;
    const char* Bb = Ab + 16384;
    #pragma unroll
    for (int ks = 0; ks < 2; ++ks) {
      int kb = ks * 64 + fq * 16;
      f16x8 af[4], bf[4];
      #pragma unroll
      for (int mi = 0; mi < 4; ++mi)
        af[mi] = *(const f16x8*)(Ab + (wr * 64 + mi * 16 + fr) * 128 + (kb ^ sw));
      #pragma unroll
      for (int ni = 0; ni < 4; ++ni)
        bf[ni] = *(const f16x8*)(Bb + (wc * 64 + ni * 16 + fr) * 128 + (kb ^ sw));
      #pragma unroll
      for (int mi = 0; mi < 4; ++mi)
        #pragma unroll
        for (int ni = 0; ni < 4; ++ni)
          acc[mi][ni] = __builtin_amdgcn_mfma_f32_16x16x32_f16(af[mi], bf[ni], acc[mi][ni], 0, 0, 0);
    }
    asm volatile("s_barrier" ::: "memory");     // all waves done reading buf[cur]
    if (t + 2 < 16) {
      stage128(A,  row0, lda, koff + (t + 2) * 64, smem + cur * 32768,         tid);
      stage128(Bt, 0,    ldb, koff + (t + 2) * 64, smem + cur * 32768 + 16384, tid);
      asm volatile("s_waitcnt vmcnt(8)" ::: "memory");  // tile t+1 landed
    } else {
      asm volatile("s_waitcnt vmcnt(0)" ::: "memory");
    }
    asm volatile("s_barrier" ::: "memory");
    cur ^= 1;
  }

  long zb = (long)blockIdx.y * (long)M_DIM * 128;
  #pragma unroll
  for (int ni = 0; ni < 4; ++ni) {
    int col = wc * 64 + ni * 16 + fr;
    #pragma unroll
    for (int mi = 0; mi < 4; ++mi) {
      long row = row0 + wr * 64 + mi * 16 + fq * 4;
      float* cp = hp + zb + row * 128 + col;
      #pragma unroll
      for (int j = 0; j < 4; ++j) cp[(long)j * 128] = acc[mi][ni][j];
    }
  }
}

// -------- main 256^2 GEMM: round-2 structure (BK=64, depth-2 counted vmcnt) -----------
// + minimal-LDS-traffic inner loop: per k-slice read af[8]+bf[4] ONCE (24 b128/K-step
// instead of 32 — B was read twice in round 2). No sync-structure change.
__global__ __launch_bounds__(512, 2) void gemm256(
    const f16* __restrict__ A, int lda, const f16* __restrict__ Bt, int ldb,
    int nkt, const float* __restrict__ bias, float* __restrict__ C, int ldc) {
  __shared__ __align__(16) char smem[131072];
  int tid = threadIdx.x;
  int wave = tid >> 6, lane = tid & 63;
  int wr = wave >> 2, wc = wave & 3;        // 2 x 4 wave grid; wave tile 128 x 64
  int fr = lane & 15, fq = lane >> 4;

  // bijective XCD swizzle: 512 wgs = 64 per XCD; n-tile fastest within an XCD
  int flat = blockIdx.x;
  int wg = (flat & 7) * 64 + (flat >> 3);
  long row0 = (long)(wg >> 4) * 256;
  long col0 = (long)(wg & 15) * 256;

  f32x4 acc[8][4] = {};

  stage256(A,  row0, lda, 0,  smem,          tid);
  stage256(Bt, col0, ldb, 0,  smem + 32768,  tid);
  stage256(A,  row0, lda, 64, smem + 65536,  tid);
  stage256(Bt, col0, ldb, 64, smem + 98304,  tid);
  asm volatile("s_waitcnt vmcnt(8)" ::: "memory");   // tile 0 landed
  asm volatile("s_barrier" ::: "memory");

  int cur = 0;
  int sw = (fr & 7) << 4;
  for (int t = 0; t < nkt; ++t) {
    const char* Ab = smem + cur * 65536;
    const char* Bb = Ab + 32768;
    #pragma unroll
    for (int ks = 0; ks < 2; ++ks) {
      int kb = ks * 64 + fq * 16;
      f16x8 af[8], bf[4];
      #pragma unroll
      for (int n2 = 0; n2 < 4; ++n2)
        bf[n2] = *(const f16x8*)(Bb + (wc * 64 + n2 * 16 + fr) * 128 + (kb ^ sw));
      #pragma unroll
      for (int m2 = 0; m2 < 8; ++m2)
        af[m2] = *(const f16x8*)(Ab + (wr * 128 + m2 * 16 + fr) * 128 + (kb ^ sw));
      #pragma unroll
      for (int m2 = 0; m2 < 8; ++m2)
        #pragma unroll
        for (int n2 = 0; n2 < 4; ++n2)
          acc[m2][n2] = __builtin_amdgcn_mfma_f32_16x16x32_f16(af[m2], bf[n2], acc[m2][n2], 0, 0, 0);
    }
    asm volatile("s_barrier" ::: "memory");           // all waves done reading buf[cur]
    if (t + 2 < nkt) {
      stage256(A,  row0, lda, (long)(t + 2) * 64, smem + cur * 65536,         tid);
      stage256(Bt, col0, ldb, (long)(t + 2) * 64, smem + cur * 65536 + 32768, tid);
      asm volatile("s_waitcnt vmcnt(8)" ::: "memory"); // tile t+1 fully landed
    } else {
      asm volatile("s_waitcnt vmcnt(0)" ::: "memory"); // drain tail
    }
    asm volatile("s_barrier" ::: "memory");
    cur ^= 1;
  }

  #pragma unroll
  for (int ni = 0; ni < 4; ++ni) {
    long col = col0 + wc * 64 + ni * 16 + fr;
    float bv = bias[col];
    #pragma unroll
    for (int mi = 0; mi < 8; ++mi) {
      long row = row0 + wr * 128 + mi * 16 + fq * 4;
      float* cp = C + row * ldc + col;
      #pragma unroll
      for (int j = 0; j < 4; ++j) cp[(long)j * ldc] = acc[mi][ni][j] + bv;
    }
  }
}

extern "C" void kernel_launch(void* const* d_in, const int* in_sizes, int n_in,
                              void* d_out, int out_size, void* d_ws, size_t ws_size,
                              hipStream_t stream) {
  (void)in_sizes; (void)n_in; (void)out_size; (void)ws_size;
  const float* x        = (const float*)d_in[0];
  const float* base_w   = (const float*)d_in[1];
  const float* base_b   = (const float*)d_in[2];
  const float* lora_A   = (const float*)d_in[3];
  const float* lora_B   = (const float*)d_in[4];
  const float* router_w = (const float*)d_in[5];
  const float* router_b = (const float*)d_in[6];
  float* out = (float*)d_out;

  char* ws = (char*)d_ws;
  f16* Ap       = (f16*)(ws + WS_AP);
  f16* Wp       = (f16*)(ws + WS_WP);
  f16* Ah       = (f16*)(ws + WS_AH);
  float* hp     = (float*)(ws + WS_HP);
  float* part   = (float*)(ws + WS_PART);
  float* logits = (float*)(ws + WS_LG);
  float* wsc    = (float*)(ws + WS_WS);

  conv_x<<<dim3(128, 4), 256, 0, stream>>>(x, Ap, part);
  conv_w<<<dim3(64, 4), 256, 0, stream>>>(base_w, Wp);
  conv_small<<<2560, 256, 0, stream>>>(lora_B, lora_A, Wp, Ah);
  router_logits<<<32, 256, 0, stream>>>(part, router_w, router_b, logits);
  router_softmax<<<1, 64, 0, stream>>>(logits, wsc);
  // h partials: M=8192, N=128, K split 4x1024 — pipelined 128^2 tiles
  gemm_h2<<<dim3(64, 4), 256, 0, stream>>>(Ap, KTOT, Ah, D_DIM, hp);
  combine_h<<<4096, 256, 0, stream>>>(hp, wsc, Ap);
  // main fused GEMM: out = [x|h'] @ [W|Bcat]^T + bias  (K = 4224 = 66*64)
  gemm256<<<512, 512, 0, stream>>>(Ap, KTOT, Wp, KTOT, NKT, base_b, out, D_DIM);
}